// Round 1
// baseline (138.939 us; speedup 1.0000x reference)
//
#include <hip/hip_runtime.h>
#include <hip/hip_bf16.h>
#include <math.h>

// NT-Xent loss, fused flash-style. N=8192 rows, D=256.
//   k_norm: row L2-normalize fp32 -> bf16 (ws), zero sumexp accumulators
//   k_sim : 128x128 bf16 MFMA tiles, exp((sim-1)/T) in-register, row-sum atomics
//   k_nll : exact fp32 pos dot + per-row nll
//   k_mean: single-block mean -> d_out
#define N_ROWS 8192
#define D_DIM  256
#define HALF_N 4096
#define INV_T      14.285714285714286f      // 1/0.07
#define SCALE_LOG2 20.609929155556620f      // log2(e)/0.07
#define EPSV   1e-8f

typedef __attribute__((ext_vector_type(8))) short bf16x8;   // 8 bf16 = 4 VGPR
typedef __attribute__((ext_vector_type(4))) float f32x4;

#define AS1 __attribute__((address_space(1)))
#define AS3 __attribute__((address_space(3)))

__device__ inline unsigned short f2bf(float x) {
    unsigned int u = __float_as_uint(x);
    unsigned int r = (u + 0x7fffu + ((u >> 16) & 1u)) >> 16;   // RNE
    return (unsigned short)r;
}

// ---------------- kernel 1: normalize rows, emit bf16; zero sumexp ----------
__global__ __launch_bounds__(256) void k_norm(const float* __restrict__ feat,
                                              unsigned short* __restrict__ fbf,
                                              float* __restrict__ sumexp) {
    const int tid = threadIdx.x;
    const int gid = blockIdx.x * 256 + tid;
    if (gid < N_ROWS) sumexp[gid] = 0.f;

    const int w = tid >> 6, lane = tid & 63;
    const int row = blockIdx.x * 4 + w;              // 2048 blocks * 4 rows
    const float4 v = ((const float4*)(feat + row * D_DIM))[lane];
    float ss = v.x*v.x + v.y*v.y + v.z*v.z + v.w*v.w;
    #pragma unroll
    for (int off = 32; off; off >>= 1) ss += __shfl_xor(ss, off);
    const float scale = 1.f / fmaxf(sqrtf(ss), EPSV);
    ushort4 o;
    o.x = f2bf(v.x * scale);
    o.y = f2bf(v.y * scale);
    o.z = f2bf(v.z * scale);
    o.w = f2bf(v.w * scale);
    ((ushort4*)(fbf + row * D_DIM))[lane] = o;
}

// ---------------- kernel 2: fused sim + exp + row-sum ----------------------
// grid = 512 blocks: rt = blockIdx>>3 (64 row tiles of 128), cs = blockIdx&7
// (col split of 1024 cols -> XCD-local B range). 4 waves 2x2, wave tile 64x64.
// A operand (64 rows x 256 k) lives in registers: 32 frags = 128 VGPR.
// B tile (128 cols x 256 k = 64 KB) staged in LDS via global_load_lds w=16,
// XOR-swizzled in 16B chunks (chunk' = chunk ^ (col&7)) -> conflict-free
// ds_read_b128 frag loads while staging stays a contiguous-per-row copy.
__global__ __launch_bounds__(256, 2) void k_sim(const unsigned short* __restrict__ fbf,
                                                float* __restrict__ sumexp) {
    __shared__ __align__(16) char Bs[65536];
    const int tid  = threadIdx.x;
    const int lane = tid & 63;
    const int w    = tid >> 6;
    const int wr   = w >> 1, wc = w & 1;
    const int q    = lane >> 4, l15 = lane & 15;
    const int rt = blockIdx.x >> 3, cs = blockIdx.x & 7;
    const int rowBase = rt * 128 + wr * 64;

    // A fragments in registers: rows rowBase + ri*16 + l15, k = t*32 + q*8 + j
    bf16x8 afrag[8][4];
    #pragma unroll
    for (int t = 0; t < 8; ++t)
        #pragma unroll
        for (int ri = 0; ri < 4; ++ri)
            afrag[t][ri] = *(const bf16x8*)(fbf + (rowBase + ri*16 + l15) * D_DIM
                                                + t*32 + q*8);

    float rsum[4][4];
    #pragma unroll
    for (int ri = 0; ri < 4; ++ri)
        #pragma unroll
        for (int r = 0; r < 4; ++r) rsum[ri][r] = 0.f;

    for (int jt = 0; jt < 8; ++jt) {
        const int colBase = cs * 1024 + jt * 128;
        const char* Bg = (const char*)(fbf + colBase * D_DIM);

        __syncthreads();                       // previous tile's reads done
        #pragma unroll
        for (int i = 0; i < 16; ++i) {         // 16 x 4 KB = 64 KB
            const int idx = i * 256 + tid;     // 16B chunk index 0..4095
            const int row = idx >> 5;          // local col 0..127
            const int cir = idx & 31;          // chunk within row
            __builtin_amdgcn_global_load_lds(
                (const AS1 void*)(Bg + row * 512 + ((cir ^ (row & 7)) << 4)),
                (AS3 void*)(Bs + idx * 16), 16, 0, 0);
        }
        __syncthreads();                       // drains vmcnt then barrier

        f32x4 acc[4][4];
        #pragma unroll
        for (int ri = 0; ri < 4; ++ri)
            #pragma unroll
            for (int ci = 0; ci < 4; ++ci) acc[ri][ci] = (f32x4){0.f, 0.f, 0.f, 0.f};

        #pragma unroll
        for (int t = 0; t < 8; ++t) {
            bf16x8 bfrag[4];
            #pragma unroll
            for (int ci = 0; ci < 4; ++ci) {
                const int c   = wc * 64 + ci * 16 + l15;   // local col
                const int cir = t * 4 + q;                 // k-chunk
                bfrag[ci] = *(const bf16x8*)(Bs + c * 512 + ((cir ^ (c & 7)) << 4));
            }
            #pragma unroll
            for (int ri = 0; ri < 4; ++ri)
                #pragma unroll
                for (int ci = 0; ci < 4; ++ci)
                    acc[ri][ci] = __builtin_amdgcn_mfma_f32_16x16x32_bf16(
                        afrag[t][ri], bfrag[ci], acc[ri][ci], 0, 0, 0);
        }

        // epilogue: exp((sim-1)/T), zero diagonal, accumulate per-row
        // C/D layout: col = l15, row = q*4 + reg
        #pragma unroll
        for (int ri = 0; ri < 4; ++ri) {
            const int gr0 = rowBase + ri * 16 + q * 4;
            #pragma unroll
            for (int ci = 0; ci < 4; ++ci) {
                const int gc = colBase + wc * 64 + ci * 16 + l15;
                #pragma unroll
                for (int r = 0; r < 4; ++r) {
                    const float e = exp2f((acc[ri][ci][r] - 1.f) * SCALE_LOG2);
                    rsum[ri][r] += (gr0 + r == gc) ? 0.f : e;
                }
            }
        }
    }

    // reduce across the 16 lanes of each quad (cols), then one atomic per row
    #pragma unroll
    for (int ri = 0; ri < 4; ++ri)
        #pragma unroll
        for (int r = 0; r < 4; ++r) {
            float s = rsum[ri][r];
            s += __shfl_xor(s, 1);
            s += __shfl_xor(s, 2);
            s += __shfl_xor(s, 4);
            s += __shfl_xor(s, 8);
            if (l15 == 0)
                atomicAdd(&sumexp[rowBase + ri * 16 + q * 4 + r], s);
        }
}

// ---------------- kernel 3: exact pos similarity + per-row nll -------------
__global__ __launch_bounds__(256) void k_nll(const float* __restrict__ feat,
                                             const float* __restrict__ sumexp,
                                             float* __restrict__ nll) {
    const int tid = threadIdx.x, w = tid >> 6, lane = tid & 63;
    const int i  = blockIdx.x * 4 + w;
    const int pc = (i + HALF_N) & (N_ROWS - 1);
    const float4 a = ((const float4*)(feat + i  * D_DIM))[lane];
    const float4 b = ((const float4*)(feat + pc * D_DIM))[lane];
    float dab = a.x*b.x + a.y*b.y + a.z*b.z + a.w*b.w;
    float daa = a.x*a.x + a.y*a.y + a.z*a.z + a.w*a.w;
    float dbb = b.x*b.x + b.y*b.y + b.z*b.z + b.w*b.w;
    #pragma unroll
    for (int off = 32; off; off >>= 1) {
        dab += __shfl_xor(dab, off);
        daa += __shfl_xor(daa, off);
        dbb += __shfl_xor(dbb, off);
    }
    if (lane == 0) {
        const float pos = dab / (fmaxf(sqrtf(daa), EPSV) * fmaxf(sqrtf(dbb), EPSV));
        nll[i] = INV_T + logf(sumexp[i]) - pos * INV_T;
    }
}

// ---------------- kernel 4: mean ------------------------------------------
__global__ __launch_bounds__(256) void k_mean(const float* __restrict__ nll,
                                              float* __restrict__ out) {
    __shared__ float red[4];
    const int tid = threadIdx.x, lane = tid & 63, w = tid >> 6;
    float s = 0.f;
    for (int i = tid; i < N_ROWS; i += 256) s += nll[i];
    #pragma unroll
    for (int off = 32; off; off >>= 1) s += __shfl_xor(s, off);
    if (lane == 0) red[w] = s;
    __syncthreads();
    if (tid == 0) out[0] = (red[0] + red[1] + red[2] + red[3]) * (1.f / N_ROWS);
}

extern "C" void kernel_launch(void* const* d_in, const int* in_sizes, int n_in,
                              void* d_out, int out_size, void* d_ws, size_t ws_size,
                              hipStream_t stream) {
    const float* feat = (const float*)d_in[0];
    char* ws = (char*)d_ws;
    unsigned short* fbf = (unsigned short*)ws;                       // 4 MB bf16
    float* sumexp = (float*)(ws + 4u * 1024u * 1024u);               // 32 KB
    float* nll    = (float*)(ws + 4u * 1024u * 1024u + 32u * 1024u); // 32 KB

    k_norm<<<N_ROWS / 4, 256, 0, stream>>>(feat, fbf, sumexp);
    k_sim <<<512,        256, 0, stream>>>(fbf, sumexp);
    k_nll <<<N_ROWS / 4, 256, 0, stream>>>(feat, sumexp, nll);
    k_mean<<<1,          256, 0, stream>>>(nll, (float*)d_out);
}